// Round 5
// baseline (148.111 us; speedup 1.0000x reference)
//
#include <hip/hip_runtime.h>
#include <math.h>

// StripePolynomial2d: out[b,c,px,py] = sum_i lut_i(xs_i), where
//   xs_i = 0.5*x + Ax[i]*px + Ay[i]*py + C0[i]   (folded position map)
//   s = clamp(floor(xs),0,511); t = 2*(xs-s)-1; P = c0 + t*(c1 + t*c2)
// 1/8 normalization folded into staged coeffs; positions 0,1 merged
// (theta=0 => identical maps => sum their weights) -> 7 tables.
//
// Wave lane mapping covers a 16px x 16py patch: since K*(a+|b|) ~= 1.0 for
// every direction, per-gather segment spread ~16 for all positions ->
// conflict-free ds_read_b64 (verified: SQ_LDS_BANK_CONFLICT == 0).
//
// R5: all-upfront x loads (4 outstanding), split c0/t accumulators to
// shorten the post-gather dependent chain, vectorized LUT staging.

#define WDIM 512
#define HDIM 512
#define SEGS 512
#define NPOS 8
#define NTAB 7     // position 0+1 merged
#define NW   1025
#define CCH  3

#define THREADS 512
#define TILE_X 128
#define TILE_Y 64
#define KITER  4                              // px advances 32 per k
#define TILES_PER_SLICE ((WDIM / TILE_X) * (HDIM / TILE_Y))  // 32

struct Params {
    float ax[NPOS];
    float ay[NPOS];
    float c0[NPOS];
};

union HalfPack {
    unsigned int u;
    _Float16 h[2];
};

__global__ __launch_bounds__(THREADS, 8)
void stripe_poly_kernel(const float* __restrict__ x,
                        const float* __restrict__ w,
                        float* __restrict__ out,
                        Params P)
{
    // 7 tables x 512 segments x 8 B = 28 KB
    __shared__ uint2 lut[NTAB][SEGS];

    const int slice = blockIdx.x / TILES_PER_SLICE;   // b*3 + c
    const int tile  = blockIdx.x % TILES_PER_SLICE;
    const int ch    = slice % CCH;
    const int bx    = (tile >> 3) * TILE_X;   // px tile origin (4 x-tiles)
    const int by    = (tile & 7) * TILE_Y;    // py tile origin (8 y-tiles)

    // Stage coefficient LUT (1/8 folded in): 3584 entries / 512 thr = 7 ea.
    // Entry s needs w[2s..2s+2]; read w[2s],w[2s+1] as one float2 (8B-aligned
    // when the row base is even; rows alternate parity so fall back cleanly).
    for (int idx = threadIdx.x; idx < NTAB * SEGS; idx += THREADS) {
        const int m = idx >> 9;            // merged table id
        const int s = idx & (SEGS - 1);
        float w0, w1, w2;
        if (m == 0) {
            const float* wa = w + (size_t)(0 * CCH + ch) * NW + 2 * s;
            const float* wb = w + (size_t)(1 * CCH + ch) * NW + 2 * s;
            w0 = wa[0] + wb[0]; w1 = wa[1] + wb[1]; w2 = wa[2] + wb[2];
        } else {
            const float* wp = w + (size_t)((m + 1) * CCH + ch) * NW + 2 * s;
            w0 = wp[0]; w1 = wp[1]; w2 = wp[2];
        }
        const float c0 = 0.125f * w1;
        const float c1 = 0.0625f * (w2 - w0);
        const float c2 = 0.125f * fmaf(0.5f, w0 + w2, -w1);
        HalfPack hp;
        hp.h[0] = (_Float16)c1;
        hp.h[1] = (_Float16)c2;
        lut[m][s] = make_uint2(__float_as_uint(c0), hp.u);
    }

    // Lane -> patch mapping: each wave covers 16px x 16py per k.
    const int tid  = threadIdx.x;
    const int wv   = tid >> 6;
    const int lane = tid & 63;
    const int px0  = bx + (wv >> 2) * 16 + (lane >> 2);  // k adds 32
    const int py   = by + (wv & 3) * 16 + (lane & 3) * 4;
    const float yf = (float)py;

    const size_t slice_off = (size_t)slice * (WDIM * HDIM);
    const size_t pbase = slice_off + (size_t)px0 * HDIM + py;

    // Issue ALL x loads up front (4 outstanding dwordx4), before the barrier
    // so they overlap staging too.
    float4 xin[KITER];
    #pragma unroll
    for (int k = 0; k < KITER; ++k)
        xin[k] = *(const float4*)(x + pbase + (size_t)(k * 32) * HDIM);

    // Hoist y-dependent part of each position map (py fixed across k).
    float gy[NTAB];
    #pragma unroll
    for (int i = 0; i < NTAB; ++i) {
        const int pi = (i == 0) ? 0 : (i + 1);
        gy[i] = fmaf(P.ay[pi], yf, P.c0[pi]);
    }

    __syncthreads();

    #pragma unroll
    for (int k = 0; k < KITER; ++k) {
        const size_t pk = pbase + (size_t)(k * 32) * HDIM;
        const float xf = (float)(px0 + k * 32);
        const float xv[4] = {xin[k].x, xin[k].y, xin[k].z, xin[k].w};
        float acc[4]  = {0.f, 0.f, 0.f, 0.f};   // t-dependent part
        float accC[4] = {0.f, 0.f, 0.f, 0.f};   // c0 part (short chain)

        #pragma unroll
        for (int i = 0; i < NTAB; ++i) {
            const int pi = (i == 0) ? 0 : (i + 1);  // source position index
            const float ay = P.ay[pi];
            const float g  = fmaf(P.ax[pi], xf, gy[i]);
            float gj[4];
            gj[0] = g;
            gj[1] = g + ay;
            gj[2] = gj[1] + ay;
            gj[3] = gj[2] + ay;
            #pragma unroll
            for (int j = 0; j < 4; ++j) {
                const float xs = fmaf(0.5f, xv[j], gj[j]);
                float sf = floorf(xs);
                sf = fminf(fmaxf(sf, 0.0f), (float)(SEGS - 1));  // v_med3
                const int s = (int)sf;
                const float t = fmaf(2.0f, xs - sf, -1.0f);
                const uint2 v = lut[i][s];                 // ds_read_b64
                HalfPack hp; hp.u = v.y;
                const float u = fmaf(t, (float)hp.h[1], (float)hp.h[0]); // v_fma_mix
                accC[j] += __uint_as_float(v.x);
                acc[j]   = fmaf(t, u, acc[j]);
            }
        }

        float4 o;
        o.x = acc[0] + accC[0];
        o.y = acc[1] + accC[1];
        o.z = acc[2] + accC[2];
        o.w = acc[3] + accC[3];
        *(float4*)(out + pk) = o;
    }
}

extern "C" void kernel_launch(void* const* d_in, const int* in_sizes, int n_in,
                              void* d_out, int out_size, void* d_ws, size_t ws_size,
                              hipStream_t stream)
{
    const float* x = (const float*)d_in[0];   // [16,3,512,512] f32
    const float* w = (const float*)d_in[1];   // [8,3,1025] f32
    float* out = (float*)d_out;

    // Host-side fold of make_positions() + position_encode + xs rescale.
    // r(x,y) = f32(cx)*x + f32(sgn*cy)*y ; extremes at grid corners (monotone).
    // xs = 0.5*xval + K*(r - rmin), K = 512*RATIO/dr  =>  Ax=K*a, Ay=K*b, C0=-K*rmin.
    Params P;
    const double ratio_f = (double)(float)(512.0 / 513.0);  // numpy casts RATIO to f32
    for (int i = 0; i < 4; ++i) {
        const double theta = (M_PI * 0.5) * ((double)i / 4.0);
        const float a   = (float)cos(theta);
        const float cyf = (float)sin(theta);
        for (int sg = 0; sg < 2; ++sg) {
            const float b = (sg == 0) ? cyf : -cyf;   // f32(sgn*cy)
            const float ax511 = a * 511.0f;
            const float by511 = b * 511.0f;
            float rmin, rmax;
            if (sg == 0) { rmin = 0.0f;  rmax = ax511 + by511; }
            else         { rmin = by511; rmax = ax511; }
            const float dr = rmax - rmin;
            const double K = 512.0 * ratio_f / (double)dr;
            const int pi = 2 * i + sg;
            P.ax[pi] = (float)(K * (double)a);
            P.ay[pi] = (float)(K * (double)b);
            P.c0[pi] = (float)(-K * (double)rmin);
        }
    }

    const int slices = in_sizes[0] / (WDIM * HDIM);  // B*C = 48
    const int blocks = slices * TILES_PER_SLICE;     // 1536
    stripe_poly_kernel<<<blocks, THREADS, 0, stream>>>(x, w, out, P);
}

// Round 6
// 119.650 us; speedup vs baseline: 1.2379x; 1.2379x over previous
//
#include <hip/hip_runtime.h>
#include <math.h>

// StripePolynomial2d: out[b,c,px,py] = sum_i lut_i(xs_i), where
//   xs_i = 0.5*x + Ax[i]*px + Ay[i]*py + C0[i]   (folded position map)
//   s = clamp(floor(xs),0,511); d = xs - s; P = a0 + d*(a1 + d*a2)
// with a0=w0/8 (f32), a1=(-3w0+4w1-w2)/8, a2=(w0-2w1+w2)/4 (f16 pair).
// 1/8 normalization folded into staged coeffs; positions 0,1 merged
// (theta=0 => identical maps => sum their weights) -> 7 tables.
//
// Wave lane mapping covers a 16px x 16py patch: since K*(a+|b|) ~= 1.0 for
// every direction, per-gather segment spread ~16 for all positions ->
// conflict-free ds_read_b64 (verified: SQ_LDS_BANK_CONFLICT == 0).
//
// R6: launch_bounds(512,6) -> ~80 VGPR budget so the 4 upfront x loads stay
// in registers (R5's (512,8)=64-VGPR cap spilled them to scratch: +120 MB
// HBM traffic, 42->72 us). 1536 blocks / 3 resident per CU = 2 clean rounds.

#define WDIM 512
#define HDIM 512
#define SEGS 512
#define NPOS 8
#define NTAB 7     // position 0+1 merged
#define NW   1025
#define CCH  3

#define THREADS 512
#define TILE_X 128
#define TILE_Y 64
#define KITER  4                              // px advances 32 per k
#define TILES_PER_SLICE ((WDIM / TILE_X) * (HDIM / TILE_Y))  // 32

struct Params {
    float ax[NPOS];
    float ay[NPOS];
    float c0[NPOS];
};

union HalfPack {
    unsigned int u;
    _Float16 h[2];
};

__global__ __launch_bounds__(THREADS, 6)
void stripe_poly_kernel(const float* __restrict__ x,
                        const float* __restrict__ w,
                        float* __restrict__ out,
                        Params P)
{
    // 7 tables x 512 segments x 8 B = 28 KB
    __shared__ uint2 lut[NTAB][SEGS];

    const int slice = blockIdx.x / TILES_PER_SLICE;   // b*3 + c
    const int tile  = blockIdx.x % TILES_PER_SLICE;
    const int ch    = slice % CCH;
    const int bx    = (tile >> 3) * TILE_X;   // px tile origin (4 x-tiles)
    const int by    = (tile & 7) * TILE_Y;    // py tile origin (8 y-tiles)

    // Lane -> patch mapping: each wave covers 16px x 16py per k.
    const int tid  = threadIdx.x;
    const int wv   = tid >> 6;
    const int lane = tid & 63;
    const int px0  = bx + (wv >> 2) * 16 + (lane >> 2);  // k adds 32
    const int py   = by + (wv & 3) * 16 + (lane & 3) * 4;
    const float yf = (float)py;

    const size_t slice_off = (size_t)slice * (WDIM * HDIM);
    const size_t pbase = slice_off + (size_t)px0 * HDIM + py;

    // Issue ALL x loads up front (4 outstanding dwordx4); they overlap the
    // LUT staging below. Kept as scalars so they live in VGPRs (no spill).
    const float4 xin0 = *(const float4*)(x + pbase);
    const float4 xin1 = *(const float4*)(x + pbase + (size_t)(1 * 32) * HDIM);
    const float4 xin2 = *(const float4*)(x + pbase + (size_t)(2 * 32) * HDIM);
    const float4 xin3 = *(const float4*)(x + pbase + (size_t)(3 * 32) * HDIM);

    // Stage coefficient LUT (1/8 folded in): 3584 entries / 512 thr = 7 ea.
    for (int idx = threadIdx.x; idx < NTAB * SEGS; idx += THREADS) {
        const int m = idx >> 9;            // merged table id
        const int s = idx & (SEGS - 1);
        float w0, w1, w2;
        if (m == 0) {
            const float* wa = w + (size_t)(0 * CCH + ch) * NW + 2 * s;
            const float* wb = w + (size_t)(1 * CCH + ch) * NW + 2 * s;
            w0 = wa[0] + wb[0]; w1 = wa[1] + wb[1]; w2 = wa[2] + wb[2];
        } else {
            const float* wp = w + (size_t)((m + 1) * CCH + ch) * NW + 2 * s;
            w0 = wp[0]; w1 = wp[1]; w2 = wp[2];
        }
        const float a0 = 0.125f * w0;
        const float a1 = 0.125f * (fmaf(4.0f, w1, -w2) - 3.0f * w0);
        const float a2 = 0.25f  * (w0 - 2.0f * w1 + w2);
        HalfPack hp;
        hp.h[0] = (_Float16)a1;
        hp.h[1] = (_Float16)a2;
        lut[m][s] = make_uint2(__float_as_uint(a0), hp.u);
    }

    // Hoist y-dependent part of each position map (py fixed across k).
    float gy[NTAB];
    #pragma unroll
    for (int i = 0; i < NTAB; ++i) {
        const int pi = (i == 0) ? 0 : (i + 1);
        gy[i] = fmaf(P.ay[pi], yf, P.c0[pi]);
    }

    __syncthreads();

    #pragma unroll
    for (int k = 0; k < KITER; ++k) {
        const size_t pk = pbase + (size_t)(k * 32) * HDIM;
        const float xf = (float)(px0 + k * 32);
        const float4 xk = (k == 0) ? xin0 : (k == 1) ? xin1 : (k == 2) ? xin2 : xin3;
        const float xv[4] = {xk.x, xk.y, xk.z, xk.w};
        float acc[4]  = {0.f, 0.f, 0.f, 0.f};   // d-dependent part
        float accC[4] = {0.f, 0.f, 0.f, 0.f};   // a0 part (short chain)

        #pragma unroll
        for (int i = 0; i < NTAB; ++i) {
            const int pi = (i == 0) ? 0 : (i + 1);  // source position index
            const float ay = P.ay[pi];
            const float g  = fmaf(P.ax[pi], xf, gy[i]);
            float gj[4];
            gj[0] = g;
            gj[1] = g + ay;
            gj[2] = gj[1] + ay;
            gj[3] = gj[2] + ay;
            #pragma unroll
            for (int j = 0; j < 4; ++j) {
                const float xs = fmaf(0.5f, xv[j], gj[j]);
                float sf = floorf(xs);
                sf = fminf(fmaxf(sf, 0.0f), (float)(SEGS - 1));  // v_med3
                const int s = (int)sf;
                const float d = xs - sf;
                const uint2 v = lut[i][s];                 // ds_read_b64
                HalfPack hp; hp.u = v.y;
                const float u = fmaf(d, (float)hp.h[1], (float)hp.h[0]); // v_fma_mix
                accC[j] += __uint_as_float(v.x);
                acc[j]   = fmaf(d, u, acc[j]);
            }
        }

        float4 o;
        o.x = acc[0] + accC[0];
        o.y = acc[1] + accC[1];
        o.z = acc[2] + accC[2];
        o.w = acc[3] + accC[3];
        *(float4*)(out + pk) = o;
    }
}

extern "C" void kernel_launch(void* const* d_in, const int* in_sizes, int n_in,
                              void* d_out, int out_size, void* d_ws, size_t ws_size,
                              hipStream_t stream)
{
    const float* x = (const float*)d_in[0];   // [16,3,512,512] f32
    const float* w = (const float*)d_in[1];   // [8,3,1025] f32
    float* out = (float*)d_out;

    // Host-side fold of make_positions() + position_encode + xs rescale.
    // r(x,y) = f32(cx)*x + f32(sgn*cy)*y ; extremes at grid corners (monotone).
    // xs = 0.5*xval + K*(r - rmin), K = 512*RATIO/dr  =>  Ax=K*a, Ay=K*b, C0=-K*rmin.
    Params P;
    const double ratio_f = (double)(float)(512.0 / 513.0);  // numpy casts RATIO to f32
    for (int i = 0; i < 4; ++i) {
        const double theta = (M_PI * 0.5) * ((double)i / 4.0);
        const float a   = (float)cos(theta);
        const float cyf = (float)sin(theta);
        for (int sg = 0; sg < 2; ++sg) {
            const float b = (sg == 0) ? cyf : -cyf;   // f32(sgn*cy)
            const float ax511 = a * 511.0f;
            const float by511 = b * 511.0f;
            float rmin, rmax;
            if (sg == 0) { rmin = 0.0f;  rmax = ax511 + by511; }
            else         { rmin = by511; rmax = ax511; }
            const float dr = rmax - rmin;
            const double K = 512.0 * ratio_f / (double)dr;
            const int pi = 2 * i + sg;
            P.ax[pi] = (float)(K * (double)a);
            P.ay[pi] = (float)(K * (double)b);
            P.c0[pi] = (float)(-K * (double)rmin);
        }
    }

    const int slices = in_sizes[0] / (WDIM * HDIM);  // B*C = 48
    const int blocks = slices * TILES_PER_SLICE;     // 1536
    stripe_poly_kernel<<<blocks, THREADS, 0, stream>>>(x, w, out, P);
}

// Round 7
// 117.342 us; speedup vs baseline: 1.2622x; 1.0197x over previous
//
#include <hip/hip_runtime.h>
#include <math.h>

// StripePolynomial2d: out[b,c,px,py] = sum_i lut_i(xs_i), where
//   xs_i = 0.5*x + Ax[i]*px + Ay[i]*py + C0[i]   (folded position map)
//   s = clamp(floor(xs),0,511); d = xs - s; P = a0 + d*(a1 + d*a2)
// a0=w0/8 (f32), a1=(-3w0+4w1-w2)/8, a2=(w0-2w1+w2)/4 (f16 pair).
// Positions 0,1 merged (theta=0 => identical maps) -> 7 tables, 28 KB LDS.
//
// R7 structure: 1024 blocks x 512 thr = exactly 4 blocks/CU resident
// (32 waves/CU, one round, no tail). Work unit = 16x16 pixel patch; one
// wave processes one patch per k (lane = 16px x 4py quad) -> conflict-free
// ds_read_b64 (K*(a+|b|) ~= 1.0 for all directions => segment spread ~16).
// Patches ordered channel-major: 48 patches/block share one channel LUT
// (2/1024 blocks re-stage once). NO barrier in the main loop -> waves
// drift, no convoys; rolling 1-deep prefetch of next patch's x.

#define WDIM 512
#define HDIM 512
#define SEGS 512
#define NPOS 8
#define NTAB 7
#define NW   1025
#define CCH  3

#define THREADS 512
#define BLOCKS  1024
#define PER_BLK 48          // patches per block
#define KITER   (PER_BLK / 8)   // 6, 8 waves each take one patch per k
#define PATCH_PER_CH 16384  // 16 slices * 1024 patches

struct Params {
    float ax[NPOS];
    float ay[NPOS];
    float c0[NPOS];
};

union HalfPack {
    unsigned int u;
    _Float16 h[2];
};

__global__ __launch_bounds__(THREADS, 8)
void stripe_poly_kernel(const float* __restrict__ x,
                        const float* __restrict__ w,
                        float* __restrict__ out,
                        Params P)
{
    __shared__ uint2 lut[NTAB][SEGS];

    const int tid  = threadIdx.x;
    const int wv   = tid >> 6;
    const int lane = tid & 63;
    const int plx  = lane >> 2;        // 0..15
    const int ply  = (lane & 3) * 4;   // 0,4,8,12

    const int qbase = blockIdx.x * PER_BLK;   // first patch of this block

    // ---- LUT staging (channel ch), used 1-2x per block ----
    auto stage = [&](int ch) {
        for (int idx = tid; idx < NTAB * SEGS; idx += THREADS) {
            const int m = idx >> 9;
            const int s = idx & (SEGS - 1);
            float w0, w1, w2;
            if (m == 0) {
                const float* wa = w + (size_t)(0 * CCH + ch) * NW + 2 * s;
                const float* wb = w + (size_t)(1 * CCH + ch) * NW + 2 * s;
                w0 = wa[0] + wb[0]; w1 = wa[1] + wb[1]; w2 = wa[2] + wb[2];
            } else {
                const float* wp = w + (size_t)((m + 1) * CCH + ch) * NW + 2 * s;
                w0 = wp[0]; w1 = wp[1]; w2 = wp[2];
            }
            const float a0 = 0.125f * w0;
            const float a1 = 0.125f * (fmaf(4.0f, w1, -w2) - 3.0f * w0);
            const float a2 = 0.25f  * (w0 - 2.0f * w1 + w2);
            HalfPack hp;
            hp.h[0] = (_Float16)a1;
            hp.h[1] = (_Float16)a2;
            lut[m][s] = make_uint2(__float_as_uint(a0), hp.u);
        }
    };

    // Patch coords for this wave at step k (q is wave-uniform).
    auto coords = [&](int k, int& ch, float& xf, float& yf, size_t& off) {
        const int q   = qbase + k * 8 + wv;
        ch            = q >> 14;              // / PATCH_PER_CH
        const int r   = q & (PATCH_PER_CH - 1);
        const int bsl = r >> 10;              // batch slice within channel
        const int pis = r & 1023;             // patch in 32x32 grid
        const int px  = ((pis >> 5) << 4) + plx;
        const int py  = ((pis & 31) << 4) + ply;
        xf = (float)px; yf = (float)py;
        off = ((size_t)(bsl * CCH + ch) << 18) + ((size_t)px << 9) + py;
    };

    int c_cur = qbase >> 14;
    stage(c_cur);

    int ch0; float xf, yf; size_t off;
    coords(0, ch0, xf, yf, off);
    float4 xin = *(const float4*)(x + off);   // overlaps staging
    __syncthreads();

    for (int k = 0; k < KITER; ++k) {
        // prefetch next patch
        int chn; float xfn, yfn; size_t offn;
        float4 xnext;
        if (k + 1 < KITER) {
            coords(k + 1, chn, xfn, yfn, offn);
            xnext = *(const float4*)(x + offn);
        }

        // channel switch (block-uniform; hits 2 of 1024 blocks, once)
        if (ch0 != c_cur) {
            __syncthreads();
            stage(ch0);
            c_cur = ch0;
            __syncthreads();
        }

        const float xv[4] = {xin.x, xin.y, xin.z, xin.w};
        float acc[4]  = {0.f, 0.f, 0.f, 0.f};
        float accC[4] = {0.f, 0.f, 0.f, 0.f};

        #pragma unroll
        for (int i = 0; i < NTAB; ++i) {
            const int pi = (i == 0) ? 0 : (i + 1);
            const float ay = P.ay[pi];
            const float g  = fmaf(P.ax[pi], xf, fmaf(ay, yf, P.c0[pi]));
            float gj[4];
            gj[0] = g;
            gj[1] = g + ay;
            gj[2] = gj[1] + ay;
            gj[3] = gj[2] + ay;
            #pragma unroll
            for (int j = 0; j < 4; ++j) {
                const float xs = fmaf(0.5f, xv[j], gj[j]);
                float sf = floorf(xs);
                sf = fminf(fmaxf(sf, 0.0f), (float)(SEGS - 1));  // v_med3
                const int s = (int)sf;
                const float d = xs - sf;
                const uint2 v = lut[i][s];                 // ds_read_b64
                HalfPack hp; hp.u = v.y;
                const float u = fmaf(d, (float)hp.h[1], (float)hp.h[0]); // v_fma_mix
                accC[j] += __uint_as_float(v.x);
                acc[j]   = fmaf(d, u, acc[j]);
            }
        }

        float4 o;
        o.x = acc[0] + accC[0];
        o.y = acc[1] + accC[1];
        o.z = acc[2] + accC[2];
        o.w = acc[3] + accC[3];
        *(float4*)(out + off) = o;

        xin = xnext; ch0 = chn; xf = xfn; yf = yfn; off = offn;
    }
}

extern "C" void kernel_launch(void* const* d_in, const int* in_sizes, int n_in,
                              void* d_out, int out_size, void* d_ws, size_t ws_size,
                              hipStream_t stream)
{
    const float* x = (const float*)d_in[0];   // [16,3,512,512] f32
    const float* w = (const float*)d_in[1];   // [8,3,1025] f32
    float* out = (float*)d_out;

    // Host-side fold of make_positions() + position_encode + xs rescale.
    // r(x,y) = f32(cx)*x + f32(sgn*cy)*y ; extremes at grid corners (monotone).
    // xs = 0.5*xval + K*(r - rmin), K = 512*RATIO/dr  =>  Ax=K*a, Ay=K*b, C0=-K*rmin.
    Params P;
    const double ratio_f = (double)(float)(512.0 / 513.0);  // numpy casts RATIO to f32
    for (int i = 0; i < 4; ++i) {
        const double theta = (M_PI * 0.5) * ((double)i / 4.0);
        const float a   = (float)cos(theta);
        const float cyf = (float)sin(theta);
        for (int sg = 0; sg < 2; ++sg) {
            const float b = (sg == 0) ? cyf : -cyf;   // f32(sgn*cy)
            const float ax511 = a * 511.0f;
            const float by511 = b * 511.0f;
            float rmin, rmax;
            if (sg == 0) { rmin = 0.0f;  rmax = ax511 + by511; }
            else         { rmin = by511; rmax = ax511; }
            const float dr = rmax - rmin;
            const double K = 512.0 * ratio_f / (double)dr;
            const int pi = 2 * i + sg;
            P.ax[pi] = (float)(K * (double)a);
            P.ay[pi] = (float)(K * (double)b);
            P.c0[pi] = (float)(-K * (double)rmin);
        }
    }

    stripe_poly_kernel<<<BLOCKS, THREADS, 0, stream>>>(x, w, out, P);
}